// Round 1
// baseline (53.400 us; speedup 1.0000x reference)
//
#include <hip/hip_runtime.h>
#include <math.h>

#define NB      8
#define NPTS    4096
#define THREADS 256
#define SLICES  4            // one m-slice per wave (wave-uniform LDS reads)
#define QPT     2            // query points per lane
#define QBLK    (64 * QPT)   // 128 queries per block
#define MSLICE  (NPTS / SLICES)  // 1024
#define QTILES  (NPTS / QBLK)    // 32

__global__ __launch_bounds__(64) void init_ws_kernel(unsigned int* ws) {
    int t = threadIdx.x;
    if (t < NB) ws[t] = 0u;
}

__global__ __launch_bounds__(THREADS) void mmpd_main(const float* __restrict__ pts,
                                                     unsigned int* __restrict__ ws) {
    __shared__ float lds[NPTS * 3];      // 48 KiB, interleaved xyzxyz...
    __shared__ float redA[THREADS];
    __shared__ float redB[THREADS];

    const int tid  = threadIdx.x;
    const int qt   = blockIdx.x;
    const int b    = blockIdx.y;
    const int lane = tid & 63;
    const int wave = tid >> 6;           // slice id: LDS reads uniform per wave

    // ---- stage the whole batch's points into LDS (straight float4 copy) ----
    {
        const float4* __restrict__ src4 =
            (const float4*)(pts + (size_t)b * (NPTS * 3));
        float4* dst4 = (float4*)lds;
        #pragma unroll
        for (int i = 0; i < (NPTS * 3 / 4) / THREADS; ++i) {  // 12 iters
            int v = tid + i * THREADS;
            dst4[v] = src4[v];
        }
    }
    __syncthreads();

    // ---- each lane owns QPT=2 query points ----
    const int q0 = qt * QBLK + lane * QPT;
    const int q1 = q0 + 1;
    const float qx0 = lds[3 * q0 + 0], qy0 = lds[3 * q0 + 1], qz0 = lds[3 * q0 + 2];
    const float qx1 = lds[3 * q1 + 0], qy1 = lds[3 * q1 + 1], qz1 = lds[3 * q1 + 2];

    float min0 = 3.0e38f, min1 = 3.0e38f;
    const int mbase = wave * MSLICE;

    #pragma unroll 4
    for (int i = 0; i < MSLICE; ++i) {
        const int m = mbase + i;
        const float px = lds[3 * m + 0];   // wave-uniform addr -> broadcast
        const float py = lds[3 * m + 1];
        const float pz = lds[3 * m + 2];

        float dx = qx0 - px, dy = qy0 - py, dz = qz0 - pz;
        float d2 = dx * dx + dy * dy + dz * dz;
        min0 = fminf(min0, (m == q0) ? 3.0e38f : d2);

        dx = qx1 - px; dy = qy1 - py; dz = qz1 - pz;
        d2 = dx * dx + dy * dy + dz * dz;
        min1 = fminf(min1, (m == q1) ? 3.0e38f : d2);
    }

    // ---- combine the 4 slices (waves) per query, then block max ----
    redA[tid] = min0;
    redB[tid] = min1;
    __syncthreads();

    if (tid < 64) {   // wave 0
        float a = fminf(fminf(redA[tid], redA[tid + 64]),
                        fminf(redA[tid + 128], redA[tid + 192]));
        float c = fminf(fminf(redB[tid], redB[tid + 64]),
                        fminf(redB[tid + 128], redB[tid + 192]));
        float v = fmaxf(a, c);            // max over this lane's 2 queries
        #pragma unroll
        for (int off = 32; off >= 1; off >>= 1)
            v = fmaxf(v, __shfl_xor(v, off));
        if (tid == 0)
            atomicMax(&ws[b], __float_as_uint(v));  // d2 >= 0: uint order == float order
    }
}

__global__ __launch_bounds__(64) void finalize_kernel(const unsigned int* __restrict__ ws,
                                                      float* __restrict__ out) {
    int t = threadIdx.x;
    if (t < NB) {
        float d2 = __uint_as_float(ws[t]);
        out[t] = fmaxf(sqrtf(d2), 8.0f);
    }
}

extern "C" void kernel_launch(void* const* d_in, const int* in_sizes, int n_in,
                              void* d_out, int out_size, void* d_ws, size_t ws_size,
                              hipStream_t stream) {
    const float* pts = (const float*)d_in[0];
    float* out = (float*)d_out;
    unsigned int* ws = (unsigned int*)d_ws;

    init_ws_kernel<<<1, 64, 0, stream>>>(ws);
    mmpd_main<<<dim3(QTILES, NB), THREADS, 0, stream>>>(pts, ws);
    finalize_kernel<<<1, 64, 0, stream>>>(ws, out);
}

// Round 2
// 19.053 us; speedup vs baseline: 2.8027x; 2.8027x over previous
//
#include <hip/hip_runtime.h>
#include <math.h>

#define NB       8
#define NPTS     4096
#define CLAMP2   64.0f            // 8.0^2, in squared-distance space

// ---- screen pass ----
#define SCREEN_S 128              // sample points per batch
#define SCREEN_T 256              // threads per screen block

// ---- exact fallback pass ----
#define THREADS  256
#define SLICES   4                // one m-slice per wave (wave-uniform LDS reads)
#define QPT      2                // query points per lane
#define QBLK     (64 * QPT)       // 128 queries per block
#define MSLICE   (NPTS / SLICES)  // 1024
#define QTILES   (NPTS / QBLK)    // 32

// ws layout: [0..31] 8 x uint atomic-max slots (d2 bits); flags at +64 bytes:
// one uint64 per 64 consecutive queries: 64 words per batch, 8 batches = 4 KiB.

// Screen: for each query, min d2 over first SCREEN_S points (self excluded).
// If that min > 64, the query MIGHT exceed the clamp -> flag it for the exact
// pass. Otherwise its min-dist <= 8 and the clamp absorbs it. Exact for all
// inputs; for Gaussian data nothing gets flagged.
__global__ __launch_bounds__(SCREEN_T)
void screen_kernel(const float* __restrict__ pts,
                   unsigned int* __restrict__ wsmax,
                   unsigned long long* __restrict__ flags) {
    __shared__ float sp[SCREEN_S * 3];
    const int tid = threadIdx.x;
    const int b   = blockIdx.y;
    const int q   = blockIdx.x * SCREEN_T + tid;
    const float* __restrict__ base = pts + (size_t)b * (NPTS * 3);

    // zero the atomic-max slots (benign multi-writer of identical 0)
    if (blockIdx.x == 0 && tid < NB) wsmax[tid] = 0u;

    if (tid < (SCREEN_S * 3 / 4))                    // 96 float4 = 1.5 KiB
        ((float4*)sp)[tid] = ((const float4*)base)[tid];
    __syncthreads();

    const float qx = base[3 * q + 0];
    const float qy = base[3 * q + 1];
    const float qz = base[3 * q + 2];

    float mn = 3.0e38f;
    #pragma unroll 8
    for (int i = 0; i < SCREEN_S; ++i) {
        const float dx = qx - sp[3 * i + 0];         // uniform addr -> broadcast
        const float dy = qy - sp[3 * i + 1];
        const float dz = qz - sp[3 * i + 2];
        const float d2 = dx * dx + dy * dy + dz * dz;
        mn = fminf(mn, (i == q) ? 3.0e38f : d2);     // exclude self
    }

    const unsigned long long m = __ballot(mn > CLAMP2);
    if ((tid & 63) == 0) flags[b * 64 + (q >> 6)] = m;
}

// Exact all-pairs min for blocks containing any flagged query.
__global__ __launch_bounds__(THREADS)
void mmpd_exact(const float* __restrict__ pts,
                unsigned int* __restrict__ wsmax,
                const unsigned long long* __restrict__ flags) {
    const int tid  = threadIdx.x;
    const int qt   = blockIdx.x;
    const int b    = blockIdx.y;

    // early exit: do any of this block's 128 queries need the exact pass?
    const unsigned long long f =
        flags[b * 64 + qt * 2] | flags[b * 64 + qt * 2 + 1];
    if (f == 0ull) return;                           // uniform branch

    __shared__ float lds[NPTS * 3];                  // 48 KiB
    __shared__ float redA[THREADS];
    __shared__ float redB[THREADS];

    const int lane = tid & 63;
    const int wave = tid >> 6;

    {
        const float4* __restrict__ src4 =
            (const float4*)(pts + (size_t)b * (NPTS * 3));
        float4* dst4 = (float4*)lds;
        #pragma unroll
        for (int i = 0; i < (NPTS * 3 / 4) / THREADS; ++i) {
            int v = tid + i * THREADS;
            dst4[v] = src4[v];
        }
    }
    __syncthreads();

    const int q0 = qt * QBLK + lane * QPT;
    const int q1 = q0 + 1;
    const float qx0 = lds[3 * q0 + 0], qy0 = lds[3 * q0 + 1], qz0 = lds[3 * q0 + 2];
    const float qx1 = lds[3 * q1 + 0], qy1 = lds[3 * q1 + 1], qz1 = lds[3 * q1 + 2];

    float min0 = 3.0e38f, min1 = 3.0e38f;
    const int mbase = wave * MSLICE;

    #pragma unroll 4
    for (int i = 0; i < MSLICE; ++i) {
        const int m = mbase + i;
        const float px = lds[3 * m + 0];             // wave-uniform -> broadcast
        const float py = lds[3 * m + 1];
        const float pz = lds[3 * m + 2];

        float dx = qx0 - px, dy = qy0 - py, dz = qz0 - pz;
        float d2 = dx * dx + dy * dy + dz * dz;
        min0 = fminf(min0, (m == q0) ? 3.0e38f : d2);

        dx = qx1 - px; dy = qy1 - py; dz = qz1 - pz;
        d2 = dx * dx + dy * dy + dz * dz;
        min1 = fminf(min1, (m == q1) ? 3.0e38f : d2);
    }

    redA[tid] = min0;
    redB[tid] = min1;
    __syncthreads();

    if (tid < 64) {
        float a = fminf(fminf(redA[tid], redA[tid + 64]),
                        fminf(redA[tid + 128], redA[tid + 192]));
        float c = fminf(fminf(redB[tid], redB[tid + 64]),
                        fminf(redB[tid + 128], redB[tid + 192]));
        float v = fmaxf(a, c);
        #pragma unroll
        for (int off = 32; off >= 1; off >>= 1)
            v = fmaxf(v, __shfl_xor(v, off));
        if (tid == 0)
            atomicMax(&wsmax[b], __float_as_uint(v));  // d2 >= 0
    }
}

__global__ __launch_bounds__(64)
void finalize_kernel(const unsigned int* __restrict__ wsmax,
                     float* __restrict__ out) {
    int t = threadIdx.x;
    if (t < NB) {
        float d2 = __uint_as_float(wsmax[t]);
        out[t] = fmaxf(sqrtf(d2), 8.0f);
    }
}

extern "C" void kernel_launch(void* const* d_in, const int* in_sizes, int n_in,
                              void* d_out, int out_size, void* d_ws, size_t ws_size,
                              hipStream_t stream) {
    const float* pts = (const float*)d_in[0];
    float* out = (float*)d_out;
    unsigned int* wsmax = (unsigned int*)d_ws;
    unsigned long long* flags = (unsigned long long*)((char*)d_ws + 64);

    screen_kernel<<<dim3(NPTS / SCREEN_T, NB), SCREEN_T, 0, stream>>>(pts, wsmax, flags);
    mmpd_exact<<<dim3(QTILES, NB), THREADS, 0, stream>>>(pts, wsmax, flags);
    finalize_kernel<<<1, 64, 0, stream>>>(wsmax, out);
}

// Round 3
// 12.137 us; speedup vs baseline: 4.3997x; 1.5698x over previous
//
#include <hip/hip_runtime.h>
#include <math.h>

#define NB       8
#define NPTS     4096
#define CLAMP    8.0f
#define CLAMP2   64.0f            // 8^2 in squared-distance space

#define THREADS  256
#define QBLK     128              // queries per block (64 lanes x 2)
#define QTILES   (NPTS / QBLK)    // 32
#define SAMPLES  128              // screen sample = first 128 points of batch

// out[b] is pre-set to 8.0 (the clamp). A block whose 128 queries ALL have a
// sampled neighbor within distance 8 contributes <= clamp -> returns without
// writing. Otherwise it computes the exact all-pairs min for its queries and
// atomicMax's max(sqrt(blockmax), 8) into out[b] (uint bit-order == float
// order for positives). Exact for every input; for Gaussian data no block
// ever takes the slow path.

__global__ __launch_bounds__(64)
void init_out_kernel(float* __restrict__ out) {
    int t = threadIdx.x;
    if (t < NB) out[t] = CLAMP;
}

__global__ __launch_bounds__(THREADS)
void mmpd_fused(const float* __restrict__ pts, float* __restrict__ out) {
    __shared__ float lds[NPTS * 3];      // 48 KiB (phase 1 uses first 1.5 KiB)
    __shared__ float redA[THREADS];
    __shared__ float redB[THREADS];
    __shared__ unsigned int flagw;

    const int tid  = threadIdx.x;
    const int qt   = blockIdx.x;
    const int b    = blockIdx.y;
    const int lane = tid & 63;
    const int wave = tid >> 6;
    const float* __restrict__ base = pts + (size_t)b * (NPTS * 3);

    // ---- phase 1: screen this block's 128 queries vs 128 sample points ----
    if (tid < (SAMPLES * 3 / 4))                     // 96 float4 = 1.5 KiB
        ((float4*)lds)[tid] = ((const float4*)base)[tid];
    __syncthreads();

    const int q0 = qt * QBLK + lane * 2;
    const int q1 = q0 + 1;
    const float2 qA = *(const float2*)(base + 3 * q0);      // 8B-aligned: 3*q0 even
    const float2 qB = *(const float2*)(base + 3 * q0 + 2);
    const float2 qC = *(const float2*)(base + 3 * q0 + 4);
    const float qx0 = qA.x, qy0 = qA.y, qz0 = qB.x;
    const float qx1 = qB.y, qy1 = qC.x, qz1 = qC.y;

    float min0 = 3.0e38f, min1 = 3.0e38f;
    {
        const int mbase = wave * (SAMPLES / 4);      // 32 samples per wave
        #pragma unroll
        for (int i = 0; i < SAMPLES / 4; ++i) {
            const int m = mbase + i;
            const float px = lds[3 * m + 0];         // wave-uniform -> broadcast
            const float py = lds[3 * m + 1];
            const float pz = lds[3 * m + 2];
            float dx = qx0 - px, dy = qy0 - py, dz = qz0 - pz;
            float d2 = dx * dx + dy * dy + dz * dz;
            min0 = fminf(min0, (m == q0) ? 3.0e38f : d2);
            dx = qx1 - px; dy = qy1 - py; dz = qz1 - pz;
            d2 = dx * dx + dy * dy + dz * dz;
            min1 = fminf(min1, (m == q1) ? 3.0e38f : d2);
        }
    }
    redA[tid] = min0;
    redB[tid] = min1;
    __syncthreads();

    if (tid < 64) {
        const float a = fminf(fminf(redA[tid], redA[tid + 64]),
                              fminf(redA[tid + 128], redA[tid + 192]));
        const float c = fminf(fminf(redB[tid], redB[tid + 64]),
                              fminf(redB[tid + 128], redB[tid + 192]));
        const unsigned long long m = __ballot((a > CLAMP2) || (c > CLAMP2));
        if (tid == 0) flagw = (m != 0ull) ? 1u : 0u;
    }
    __syncthreads();

    if (flagw == 0u) return;   // all 128 queries have min-dist <= 8: clamp absorbs

    // ---- phase 2 (rare): exact all-pairs min for this block's queries ----
    {
        const float4* __restrict__ src4 = (const float4*)base;
        float4* dst4 = (float4*)lds;
        #pragma unroll
        for (int i = 0; i < (NPTS * 3 / 4) / THREADS; ++i) {  // 12 iters
            const int v = tid + i * THREADS;
            dst4[v] = src4[v];
        }
    }
    __syncthreads();

    min0 = 3.0e38f; min1 = 3.0e38f;
    const int mbase = wave * (NPTS / 4);             // 1024 points per wave
    #pragma unroll 4
    for (int i = 0; i < NPTS / 4; ++i) {
        const int m = mbase + i;
        const float px = lds[3 * m + 0];
        const float py = lds[3 * m + 1];
        const float pz = lds[3 * m + 2];
        float dx = qx0 - px, dy = qy0 - py, dz = qz0 - pz;
        float d2 = dx * dx + dy * dy + dz * dz;
        min0 = fminf(min0, (m == q0) ? 3.0e38f : d2);
        dx = qx1 - px; dy = qy1 - py; dz = qz1 - pz;
        d2 = dx * dx + dy * dy + dz * dz;
        min1 = fminf(min1, (m == q1) ? 3.0e38f : d2);
    }

    __syncthreads();           // lds/red reuse barrier
    redA[tid] = min0;
    redB[tid] = min1;
    __syncthreads();

    if (tid < 64) {
        const float a = fminf(fminf(redA[tid], redA[tid + 64]),
                              fminf(redA[tid + 128], redA[tid + 192]));
        const float c = fminf(fminf(redB[tid], redB[tid + 64]),
                              fminf(redB[tid + 128], redB[tid + 192]));
        float v = fmaxf(a, c);
        #pragma unroll
        for (int off = 32; off >= 1; off >>= 1)
            v = fmaxf(v, __shfl_xor(v, off));
        if (tid == 0)
            atomicMax((unsigned int*)&out[b],
                      __float_as_uint(fmaxf(sqrtf(v), CLAMP)));
    }
}

extern "C" void kernel_launch(void* const* d_in, const int* in_sizes, int n_in,
                              void* d_out, int out_size, void* d_ws, size_t ws_size,
                              hipStream_t stream) {
    const float* pts = (const float*)d_in[0];
    float* out = (float*)d_out;

    init_out_kernel<<<1, 64, 0, stream>>>(out);
    mmpd_fused<<<dim3(QTILES, NB), THREADS, 0, stream>>>(pts, out);
}